// Round 19
// baseline (434.081 us; speedup 1.0000x reference)
//
#include <hip/hip_runtime.h>
#include <hip/hip_fp16.h>
#include <cstdint>
#include <cstddef>

typedef _Float16 f16x8 __attribute__((ext_vector_type(8)));
typedef _Float16 f16x4 __attribute__((ext_vector_type(4)));
typedef float    f32x4 __attribute__((ext_vector_type(4)));

// ---------------------------------------------------------------------------
// fake-quant with fractional bit-width interpolation (matches jax reference)
// ---------------------------------------------------------------------------
__device__ __forceinline__ float quant_interp(float v, float alpha) {
    float a    = fmaxf(alpha, 1.0f);
    float blo  = floorf(a);
    float frac = a - blo;
    float slo  = exp2f(blo) - 1.0f;
    float shi  = 2.0f * slo + 1.0f;
    float rslo = __builtin_amdgcn_rcpf(slo);
    float rshi = __builtin_amdgcn_rcpf(shi);
    float c    = fminf(fmaxf(v, -1.0f), 1.0f);
    float qlo  = rintf(c * slo) * rslo;
    float qhi  = rintf(c * shi) * rshi;
    return (1.0f - frac) * qlo + frac * qhi;
}

// ---------------------------------------------------------------------------
// column mean of alpha_a [OUT][IN] -> a_feat [IN] (R18, frozen)
// ---------------------------------------------------------------------------
__global__ void colsum_partial4_kernel(const float* __restrict__ aA,
                                       float* __restrict__ partial,
                                       int IN, int rows_per) {
    int c4 = blockIdx.x * blockDim.x + threadIdx.x;
    size_t r0 = (size_t)blockIdx.y * rows_per;
    f32x4 s = {0.f, 0.f, 0.f, 0.f};
    for (int r = 0; r < rows_per; ++r)
        s += *(const f32x4*)(aA + (r0 + r) * (size_t)IN + (size_t)c4 * 4);
    *(f32x4*)(partial + (size_t)blockIdx.y * IN + (size_t)c4 * 4) = s;
}

__global__ void colsum_final4_kernel(const float* __restrict__ partial,
                                     float* __restrict__ afeat,
                                     int IN, int nchunk, float inv) {
    int c4 = blockIdx.x * blockDim.x + threadIdx.x;
    f32x4 s = {0.f, 0.f, 0.f, 0.f};
    for (int c = 0; c < nchunk; ++c)
        s += *(const f32x4*)(partial + (size_t)c * IN + (size_t)c4 * 4);
    *(f32x4*)(afeat + (size_t)c4 * 4) = s * inv;
}

// ---------------------------------------------------------------------------
// fused quantize (R18, frozen): x hoisted-alpha path + w per-element
// ---------------------------------------------------------------------------
__global__ void quant_xw8_kernel(const float* __restrict__ x,
                                 const float* __restrict__ afeat,
                                 f16x8* __restrict__ qx,
                                 const float* __restrict__ w,
                                 const float* __restrict__ aw,
                                 f16x8* __restrict__ qw,
                                 int IN, size_t nx8, size_t nw8) {
    const size_t t0 = (size_t)blockIdx.x * blockDim.x + threadIdx.x;
    const size_t stride = (size_t)gridDim.x * blockDim.x;

    if (((stride * 8) % (size_t)IN) == 0) {
        const int col = (int)((t0 * 8) % (size_t)IN);
        f32x4 a0 = *(const f32x4*)(afeat + col);
        f32x4 a1 = *(const f32x4*)(afeat + col + 4);
        f32x4 fr0, sl0, rl0, sh0, rh0, fr1, sl1, rl1, sh1, rh1;
        #pragma unroll
        for (int j = 0; j < 4; ++j) {
            float a = fmaxf(a0[j], 1.0f); float b = floorf(a);
            fr0[j] = a - b; sl0[j] = exp2f(b) - 1.0f; sh0[j] = 2.0f * sl0[j] + 1.0f;
            rl0[j] = __builtin_amdgcn_rcpf(sl0[j]);
            rh0[j] = __builtin_amdgcn_rcpf(sh0[j]);
            a = fmaxf(a1[j], 1.0f); b = floorf(a);
            fr1[j] = a - b; sl1[j] = exp2f(b) - 1.0f; sh1[j] = 2.0f * sl1[j] + 1.0f;
            rl1[j] = __builtin_amdgcn_rcpf(sl1[j]);
            rh1[j] = __builtin_amdgcn_rcpf(sh1[j]);
        }
        for (size_t i = t0; i < nx8; i += stride) {
            size_t e = i * 8;
            f32x4 x0 = *(const f32x4*)(x + e);
            f32x4 x1 = *(const f32x4*)(x + e + 4);
            f16x8 o;
            #pragma unroll
            for (int j = 0; j < 4; ++j) {
                float c = fminf(fmaxf(x0[j], -1.0f), 1.0f);
                o[j] = (_Float16)((1.0f - fr0[j]) * (rintf(c * sl0[j]) * rl0[j])
                                  + fr0[j]        * (rintf(c * sh0[j]) * rh0[j]));
            }
            #pragma unroll
            for (int j = 0; j < 4; ++j) {
                float c = fminf(fmaxf(x1[j], -1.0f), 1.0f);
                o[4 + j] = (_Float16)((1.0f - fr1[j]) * (rintf(c * sl1[j]) * rl1[j])
                                      + fr1[j]        * (rintf(c * sh1[j]) * rh1[j]));
            }
            qx[i] = o;
        }
    } else {
        for (size_t i = t0; i < nx8; i += stride) {
            size_t e = i * 8;
            int col = (int)(e % (size_t)IN);
            f32x4 x0 = *(const f32x4*)(x + e);
            f32x4 x1 = *(const f32x4*)(x + e + 4);
            f32x4 a0 = *(const f32x4*)(afeat + col);
            f32x4 a1 = *(const f32x4*)(afeat + col + 4);
            f16x8 o;
            #pragma unroll
            for (int j = 0; j < 4; ++j) o[j]     = (_Float16)quant_interp(x0[j], a0[j]);
            #pragma unroll
            for (int j = 0; j < 4; ++j) o[4 + j] = (_Float16)quant_interp(x1[j], a1[j]);
            qx[i] = o;
        }
    }

    for (size_t i = t0; i < nw8; i += stride) {
        size_t k = i * 8;
        f32x4 w0 = *(const f32x4*)(w + k);
        f32x4 w1 = *(const f32x4*)(w + k + 4);
        f32x4 a0 = *(const f32x4*)(aw + k);
        f32x4 a1 = *(const f32x4*)(aw + k + 4);
        f16x8 o;
        #pragma unroll
        for (int j = 0; j < 4; ++j) o[j]     = (_Float16)quant_interp(w0[j], a0[j]);
        #pragma unroll
        for (int j = 0; j < 4; ++j) o[4 + j] = (_Float16)quant_interp(w1[j], a1[j]);
        qw[i] = o;
    }
}

// ---------------------------------------------------------------------------
// 256x256 NT GEMM, fp16/fp32 — m201-FAITHFUL 4-phase/K-tile cadence.
//   Differences from all prior attempts (R2/R5 lockstep, R6 barrier-light):
//   * minimal reads/phase (m201's "4 or 8 ds_read_b128"): P1 af(mh0,ks0)+bf0
//     [8], P2 af(mh1,ks0) [4], P3 af(mh0,ks1)+bf1 [8], P4 af(mh1,ks1) [4];
//     bf per-ks persistent across the tile; af2[4] rotates.
//   * two barriers per phase with lgkm0+sched_barrier between (m201 §5
//     template): reads issue pre-barrier; MFMA cluster post-barrier. The
//     read/MFMA overlap is CROSS-WAVE: a wave exiting its MFMA cluster runs
//     the next phase's reads while its SIMD partner is still in MFMA.
//   * ONE counted gate per K-tile (vmcnt(4) at P4-end), not per phase —
//     drains exactly tile t+1; leaves A0,B0(t+2) in flight (2-4 phase
//     flight >> 900cyc HBM). Induction: entering every tile queue =
//     [A0(t+1),B0(t+1)]. Prologue = 12 loads + GATE(4).
//   * stages: P1: B1(t+1); P2: A1(t+1); P4: A0(t+2)+B0(t+2). WAR: each
//     stage >=1 barrier after its target region's last retired read
//     (A0/B0(t+2) deliberately NOT in P3, where they'd race P3's own reads).
//   Tail: t >= nkt-2 gates 0 (stage-skips shrink the queue).
//   XOR slot swizzle unchanged (inverse on GLOBAL source, rule #21).
// ---------------------------------------------------------------------------
__device__ __forceinline__ void gload_lds16(const void* g, void* l) {
    __builtin_amdgcn_global_load_lds(
        (const __attribute__((address_space(1))) void*)g,
        (__attribute__((address_space(3))) void*)l, 16, 0, 0);
}

__device__ __forceinline__ f16x8 lds_frag(const _Float16* buf, int row, int ks, int hi) {
    const int sl = (ks * 4 + hi) ^ (row & 7);
    return *(const f16x8*)((const char*)buf + row * 128 + sl * 16);
}

#define GATE(N)  asm volatile("s_waitcnt vmcnt(" N ")" ::: "memory")
#define LGKM0()  asm volatile("s_waitcnt lgkmcnt(0)" ::: "memory")
#define BAR()    __builtin_amdgcn_s_barrier()

#define READ_AF(BUF, MH, KS)                                                 \
    _Pragma("unroll")                                                        \
    for (int mi = 0; mi < 4; ++mi)                                           \
        af2[mi] = lds_frag(BUF, (MH) * 128 + wm * 64 + mi * 16 + r15, KS, hi);

#define READ_BX(BUF, KS, DST)                                                \
    _Pragma("unroll")                                                        \
    for (int nf = 0; nf < 4; ++nf)                                           \
        DST[nf] = lds_frag(BUF, (nf >> 1) * 128 + wn * 32 + (nf & 1) * 16 + r15, KS, hi);

#define MFMA16(MH, BF)                                                       \
    __builtin_amdgcn_s_setprio(1);                                           \
    _Pragma("unroll")                                                        \
    for (int mi = 0; mi < 4; ++mi)                                           \
        _Pragma("unroll")                                                    \
        for (int nf = 0; nf < 4; ++nf)                                       \
            acc[(MH) * 4 + mi][nf] = __builtin_amdgcn_mfma_f32_16x16x32_f16( \
                af2[mi], BF[nf], acc[(MH) * 4 + mi][nf], 0, 0, 0);           \
    __builtin_amdgcn_s_setprio(0);

// which: 0=A0 1=A1 2=B0 3=B1
#define TILE4(T, GEND)                                                       \
  {                                                                          \
    const _Float16* Ab = sA[(T) & 1];                                        \
    const _Float16* Bb = sB[(T) & 1];                                        \
    /* P1 (mh0,ks0) */                                                       \
    READ_AF(Ab, 0, 0);                                                       \
    READ_BX(Bb, 0, bf0);                                                     \
    STAGE((T) + 1, 3);                                                       \
    BAR(); LGKM0(); __builtin_amdgcn_sched_barrier(0);                       \
    MFMA16(0, bf0);                                                          \
    BAR();                                                                   \
    /* P2 (mh1,ks0) */                                                       \
    READ_AF(Ab, 1, 0);                                                       \
    STAGE((T) + 1, 1);                                                       \
    BAR(); LGKM0(); __builtin_amdgcn_sched_barrier(0);                       \
    MFMA16(1, bf0);                                                          \
    BAR();                                                                   \
    /* P3 (mh0,ks1) */                                                       \
    READ_AF(Ab, 0, 1);                                                       \
    READ_BX(Bb, 1, bf1);                                                     \
    BAR(); LGKM0(); __builtin_amdgcn_sched_barrier(0);                       \
    MFMA16(0, bf1);                                                          \
    BAR();                                                                   \
    /* P4 (mh1,ks1): stage t+2's A0,B0 (their last reads retired in P3) */   \
    READ_AF(Ab, 1, 1);                                                       \
    STAGE((T) + 2, 0); STAGE((T) + 2, 2);                                    \
    BAR(); LGKM0(); __builtin_amdgcn_sched_barrier(0);                       \
    MFMA16(1, bf1);                                                          \
    GATE(GEND); BAR();                                                       \
  }

__global__ __launch_bounds__(512, 2) void gemm_m4_kernel(
    const _Float16* __restrict__ A,   // [M][K] qx
    const _Float16* __restrict__ B,   // [N][K] qw
    const float* __restrict__ bias,   // [N]
    float* __restrict__ C,            // [M][N]
    int M, int N, int K)
{
    constexpr int BK = 64;
    __shared__ _Float16 sA[2][256 * BK];   // 64 KiB
    __shared__ _Float16 sB[2][256 * BK];   // 64 KiB

    const int tid  = (int)threadIdx.x;
    const int lane = tid & 63;
    const int wave = tid >> 6;
    const int wm   = wave >> 2;    // 0..1
    const int wn   = wave & 3;     // 0..3
    const int r15  = lane & 15;
    const int hi   = lane >> 4;

    const int nbx = N >> 8;
    const int nwg = (M >> 8) * nbx;
    const int bid = (int)blockIdx.x;
    const int swz = (nwg & 7) ? bid : ((bid & 7) * (nwg >> 3) + (bid >> 3));
    const size_t bm0 = (size_t)(swz / nbx) << 8;
    const size_t bn0 = (size_t)(swz % nbx) << 8;

    const int nkt = K / BK;
    const _Float16* Agb = A + bm0 * K;
    const _Float16* Bgb = B + bn0 * K;

    auto STAGE = [&](int tile, int which) {
        if (tile >= nkt) return;
        const _Float16* g = (which < 2 ? Agb : Bgb) + (size_t)tile * BK;
        _Float16* lb = (which < 2 ? sA[tile & 1] : sB[tile & 1]);
        const int rb = (which & 1) << 7;
        #pragma unroll
        for (int rr = 0; rr < 2; ++rr) {
            const int row = rb + rr * 64 + (tid >> 3);
            const int sg  = (tid & 7) ^ (row & 7);
            gload_lds16(g + (size_t)row * K + sg * 8,
                        (char*)lb + ((rb + rr * 64) << 7) + (wave << 10));
        }
    };

    f32x4 acc[8][4] = {};
    f16x8 af2[4], bf0[4], bf1[4];

    // prologue: tile0 full (A0,B0,B1,A1) + A0(1),B0(1) = 12 loads.
    // GATE(4) drains all of tile0, leaves [A0(1),B0(1)] = steady invariant.
    STAGE(0, 0); STAGE(0, 2); STAGE(0, 3); STAGE(0, 1);
    STAGE(1, 0); STAGE(1, 2);
    GATE("4"); BAR();

    int t = 0;
    for (; t < nkt - 2; ++t)
        TILE4(t, "4");
    for (; t < nkt; ++t)           // tail: stages skip -> full drain
        TILE4(t, "0");

    // epilogue: C/D layout col = lane&15, row = (lane>>4)*4 + reg
    #pragma unroll
    for (int nf = 0; nf < 4; ++nf) {
        const size_t col = bn0 + (size_t)((nf >> 1) * 128 + wn * 32 + (nf & 1) * 16 + r15);
        const float bv = bias[col];
        #pragma unroll
        for (int mf = 0; mf < 8; ++mf) {
            const size_t row0 = bm0 + (size_t)((mf >> 2) * 128 + wm * 64 + (mf & 3) * 16 + hi * 4);
            #pragma unroll
            for (int r = 0; r < 4; ++r)
                C[(row0 + r) * N + col] = acc[mf][nf][r] + bv;
        }
    }
}

// ---------------------------------------------------------------------------
extern "C" void kernel_launch(void* const* d_in, const int* in_sizes, int n_in,
                              void* d_out, int out_size, void* d_ws, size_t ws_size,
                              hipStream_t stream) {
    const float* x    = (const float*)d_in[0];
    const float* w    = (const float*)d_in[1];
    const float* bias = (const float*)d_in[2];
    const float* aw   = (const float*)d_in[3];
    const float* aA   = (const float*)d_in[4];

    const int    OUT = in_sizes[2];
    const size_t wsz = (size_t)in_sizes[1];
    const int    IN  = (int)(wsz / OUT);
    const int    M   = in_sizes[0] / IN;    // 8192
    const int    N   = OUT;                 // 4096
    const int    K   = IN;                  // 4096

    char* ws = (char*)d_ws;
    _Float16* qx = (_Float16*)ws;                                   // M*K*2
    _Float16* qw = (_Float16*)(ws + (size_t)M * K * 2);             // N*K*2
    float* afeat   = (float*)(ws + (size_t)M * K * 2 + (size_t)N * K * 2);
    float* partial = afeat + K;                                     // 64*K

    const int NCHUNK = 64;
    dim3 g1(K / 1024, NCHUNK);
    colsum_partial4_kernel<<<g1, 256, 0, stream>>>(aA, partial, K, OUT / NCHUNK);
    colsum_final4_kernel<<<K / 1024, 256, 0, stream>>>(partial, afeat, K, NCHUNK,
                                                       1.0f / (float)OUT);

    const size_t nx8 = (size_t)M * K / 8;
    const size_t nw8 = (size_t)N * K / 8;
    quant_xw8_kernel<<<2048, 256, 0, stream>>>(x, afeat, (f16x8*)qx,
                                               w, aw, (f16x8*)qw,
                                               K, nx8, nw8);

    const int nwg = (M / 256) * (N / 256);
    gemm_m4_kernel<<<nwg, 512, 0, stream>>>(qx, qw, bias, (float*)d_out,
                                            M, N, K);
}

// Round 20
// 410.086 us; speedup vs baseline: 1.0585x; 1.0585x over previous
//
#include <hip/hip_runtime.h>
#include <hip/hip_fp16.h>
#include <cstdint>
#include <cstddef>

typedef _Float16 f16x8 __attribute__((ext_vector_type(8)));
typedef _Float16 f16x4 __attribute__((ext_vector_type(4)));
typedef float    f32x4 __attribute__((ext_vector_type(4)));

// ---------------------------------------------------------------------------
// fake-quant with fractional bit-width interpolation (matches jax reference)
// ---------------------------------------------------------------------------
__device__ __forceinline__ float quant_interp(float v, float alpha) {
    float a    = fmaxf(alpha, 1.0f);
    float blo  = floorf(a);
    float frac = a - blo;
    float slo  = exp2f(blo) - 1.0f;
    float shi  = 2.0f * slo + 1.0f;
    float rslo = __builtin_amdgcn_rcpf(slo);
    float rshi = __builtin_amdgcn_rcpf(shi);
    float c    = fminf(fmaxf(v, -1.0f), 1.0f);
    float qlo  = rintf(c * slo) * rslo;
    float qhi  = rintf(c * shi) * rshi;
    return (1.0f - frac) * qlo + frac * qhi;
}

// ---------------------------------------------------------------------------
// column mean of alpha_a [OUT][IN] -> a_feat [IN] (R18, frozen)
// ---------------------------------------------------------------------------
__global__ void colsum_partial4_kernel(const float* __restrict__ aA,
                                       float* __restrict__ partial,
                                       int IN, int rows_per) {
    int c4 = blockIdx.x * blockDim.x + threadIdx.x;
    size_t r0 = (size_t)blockIdx.y * rows_per;
    f32x4 s = {0.f, 0.f, 0.f, 0.f};
    for (int r = 0; r < rows_per; ++r)
        s += *(const f32x4*)(aA + (r0 + r) * (size_t)IN + (size_t)c4 * 4);
    *(f32x4*)(partial + (size_t)blockIdx.y * IN + (size_t)c4 * 4) = s;
}

__global__ void colsum_final4_kernel(const float* __restrict__ partial,
                                     float* __restrict__ afeat,
                                     int IN, int nchunk, float inv) {
    int c4 = blockIdx.x * blockDim.x + threadIdx.x;
    f32x4 s = {0.f, 0.f, 0.f, 0.f};
    for (int c = 0; c < nchunk; ++c)
        s += *(const f32x4*)(partial + (size_t)c * IN + (size_t)c4 * 4);
    *(f32x4*)(afeat + (size_t)c4 * 4) = s * inv;
}

// ---------------------------------------------------------------------------
// fused quantize (R18, frozen): x hoisted-alpha path + w per-element
// ---------------------------------------------------------------------------
__global__ void quant_xw8_kernel(const float* __restrict__ x,
                                 const float* __restrict__ afeat,
                                 f16x8* __restrict__ qx,
                                 const float* __restrict__ w,
                                 const float* __restrict__ aw,
                                 f16x8* __restrict__ qw,
                                 int IN, size_t nx8, size_t nw8) {
    const size_t t0 = (size_t)blockIdx.x * blockDim.x + threadIdx.x;
    const size_t stride = (size_t)gridDim.x * blockDim.x;

    if (((stride * 8) % (size_t)IN) == 0) {
        const int col = (int)((t0 * 8) % (size_t)IN);
        f32x4 a0 = *(const f32x4*)(afeat + col);
        f32x4 a1 = *(const f32x4*)(afeat + col + 4);
        f32x4 fr0, sl0, rl0, sh0, rh0, fr1, sl1, rl1, sh1, rh1;
        #pragma unroll
        for (int j = 0; j < 4; ++j) {
            float a = fmaxf(a0[j], 1.0f); float b = floorf(a);
            fr0[j] = a - b; sl0[j] = exp2f(b) - 1.0f; sh0[j] = 2.0f * sl0[j] + 1.0f;
            rl0[j] = __builtin_amdgcn_rcpf(sl0[j]);
            rh0[j] = __builtin_amdgcn_rcpf(sh0[j]);
            a = fmaxf(a1[j], 1.0f); b = floorf(a);
            fr1[j] = a - b; sl1[j] = exp2f(b) - 1.0f; sh1[j] = 2.0f * sl1[j] + 1.0f;
            rl1[j] = __builtin_amdgcn_rcpf(sl1[j]);
            rh1[j] = __builtin_amdgcn_rcpf(sh1[j]);
        }
        for (size_t i = t0; i < nx8; i += stride) {
            size_t e = i * 8;
            f32x4 x0 = *(const f32x4*)(x + e);
            f32x4 x1 = *(const f32x4*)(x + e + 4);
            f16x8 o;
            #pragma unroll
            for (int j = 0; j < 4; ++j) {
                float c = fminf(fmaxf(x0[j], -1.0f), 1.0f);
                o[j] = (_Float16)((1.0f - fr0[j]) * (rintf(c * sl0[j]) * rl0[j])
                                  + fr0[j]        * (rintf(c * sh0[j]) * rh0[j]));
            }
            #pragma unroll
            for (int j = 0; j < 4; ++j) {
                float c = fminf(fmaxf(x1[j], -1.0f), 1.0f);
                o[4 + j] = (_Float16)((1.0f - fr1[j]) * (rintf(c * sl1[j]) * rl1[j])
                                      + fr1[j]        * (rintf(c * sh1[j]) * rh1[j]));
            }
            qx[i] = o;
        }
    } else {
        for (size_t i = t0; i < nx8; i += stride) {
            size_t e = i * 8;
            int col = (int)(e % (size_t)IN);
            f32x4 x0 = *(const f32x4*)(x + e);
            f32x4 x1 = *(const f32x4*)(x + e + 4);
            f32x4 a0 = *(const f32x4*)(afeat + col);
            f32x4 a1 = *(const f32x4*)(afeat + col + 4);
            f16x8 o;
            #pragma unroll
            for (int j = 0; j < 4; ++j) o[j]     = (_Float16)quant_interp(x0[j], a0[j]);
            #pragma unroll
            for (int j = 0; j < 4; ++j) o[4 + j] = (_Float16)quant_interp(x1[j], a1[j]);
            qx[i] = o;
        }
    }

    for (size_t i = t0; i < nw8; i += stride) {
        size_t k = i * 8;
        f32x4 w0 = *(const f32x4*)(w + k);
        f32x4 w1 = *(const f32x4*)(w + k + 4);
        f32x4 a0 = *(const f32x4*)(aw + k);
        f32x4 a1 = *(const f32x4*)(aw + k + 4);
        f16x8 o;
        #pragma unroll
        for (int j = 0; j < 4; ++j) o[j]     = (_Float16)quant_interp(w0[j], a0[j]);
        #pragma unroll
        for (int j = 0; j < 4; ++j) o[4 + j] = (_Float16)quant_interp(w1[j], a1[j]);
        qw[i] = o;
    }
}

// ---------------------------------------------------------------------------
// 128x256 NT GEMM, fp16 in / fp32 out — COUNTED-GATE + 2-BLOCK/CU TLP.
//   The untested lever: R1 had multi-block TLP but vmcnt(0)/tile (35%);
//   R12 has counted gates but 1 block/CU (49.5%). m114: independent waves
//   co-schedule MFMA+memory pipes automatically — needs co-resident blocks
//   AND non-draining gates. Geometry: 8 waves (2M x 4N) of 64x64 wave-tiles
//   -> acc[4][4] f32x4 = 64 VGPR -> fits the 128-reg cap at 4 waves/SIMD
//   (__launch_bounds__(512,4) = 2 blocks/CU). LDS: 3-buffer rotation x
//   (A 8K + B 16K) = 72 KiB -> 2 blocks = 144 KiB <= 160.
//   Per K-tile t (BK=32): stage(t+2) -> buf[(t+2)%3] (3 gload_lds);
//   8 ds_read_b128 (af 4 + bf 4); 16 MFMA; GATE(3) [drains stage(t+1),
//   leaves t+2's 3 in flight, 2-tile flight >> HBM latency]; s_barrier.
//   Induction: queue entering every tile = [stage(t+1)]. WAR: stage(t+2)
//   writes buf[(t-1)%3], whose reads retired before t-1's barrier.
//   Swizzle (R16-verified conflict-free): slot = hi ^ ((row>>1)&3), inverse
//   pre-applied to the GLOBAL source, linear LDS dest (rule #21).
//   Tail (t >= nkt-2): stages skip -> GATE(0).
// ---------------------------------------------------------------------------
__device__ __forceinline__ void gload_lds16(const void* g, void* l) {
    __builtin_amdgcn_global_load_lds(
        (const __attribute__((address_space(1))) void*)g,
        (__attribute__((address_space(3))) void*)l, 16, 0, 0);
}

__device__ __forceinline__ f16x8 lds_frag32(const _Float16* buf, int row, int hi) {
    const int sl = hi ^ ((row >> 1) & 3);
    return *(const f16x8*)((const char*)buf + row * 64 + sl * 16);
}

#define GATE(N)  asm volatile("s_waitcnt vmcnt(" N ")" ::: "memory")
#define BAR()    asm volatile("s_barrier" ::: "memory")

__global__ __launch_bounds__(512, 4) void gemm_tlp_kernel(
    const _Float16* __restrict__ A,   // [M][K] qx
    const _Float16* __restrict__ B,   // [N][K] qw
    const float* __restrict__ bias,   // [N]
    float* __restrict__ C,            // [M][N]
    int M, int N, int K)
{
    constexpr int BK = 32;
    __shared__ char sAll[3 * 24576];   // 72 KiB: 3 bufs x (A 8K + B 16K)

    const int tid  = (int)threadIdx.x;
    const int lane = tid & 63;
    const int wave = tid >> 6;
    const int wm   = wave >> 2;    // 0..1  (M half: 64 rows each)
    const int wn   = wave & 3;     // 0..3  (N quarter: 64 cols each)
    const int r15  = lane & 15;
    const int hi   = lane >> 4;

    const int nbx = N >> 8;                  // 256-wide col tiles
    const int nwg = (M >> 7) * nbx;          // 128-tall row tiles
    const int bid = (int)blockIdx.x;
    const int swz = (nwg & 7) ? bid : ((bid & 7) * (nwg >> 3) + (bid >> 3));
    const size_t bm0 = (size_t)(swz / nbx) << 7;
    const size_t bn0 = (size_t)(swz % nbx) << 8;

    const int nkt = K / BK;
    const _Float16* Agb = A + bm0 * K;
    const _Float16* Bgb = B + bn0 * K;

    // stage one BK=32 tile: A 128 rows (1 load/thread) + B 256 rows (2)
    auto STAGE = [&](int tile) {
        if (tile >= nkt) return;
        const int bsel = tile % 3;
        char* base = sAll + bsel * 24576;
        {
            const int row = tid >> 2;
            const int sg  = (tid & 3) ^ ((row >> 1) & 3);
            gload_lds16(Agb + (size_t)row * K + (size_t)tile * BK + sg * 8,
                        base + tid * 16);
        }
        #pragma unroll
        for (int p = 0; p < 2; ++p) {
            const int row = p * 128 + (tid >> 2);
            const int sg  = (tid & 3) ^ ((row >> 1) & 3);
            gload_lds16(Bgb + (size_t)row * K + (size_t)tile * BK + sg * 8,
                        base + 8192 + p * 8192 + tid * 16);
        }
    };

    f32x4 acc[4][4] = {};
    f16x8 af[4], bf[4];

    // prologue: stage tiles 0,1 (6 loads); GATE(3) drains tile0; publish.
    // Entering t=0: queue = [stage(1)] = the steady-state invariant.
    STAGE(0); STAGE(1);
    GATE("3"); BAR();

    for (int t = 0; t < nkt; ++t) {
        const int bsel = t % 3;
        const _Float16* Ab = (const _Float16*)(sAll + bsel * 24576);
        const _Float16* Bb = (const _Float16*)(sAll + bsel * 24576 + 8192);

        STAGE(t + 2);

        #pragma unroll
        for (int mi = 0; mi < 4; ++mi)
            af[mi] = lds_frag32(Ab, wm * 64 + mi * 16 + r15, hi);
        #pragma unroll
        for (int nf = 0; nf < 4; ++nf)
            bf[nf] = lds_frag32(Bb, wn * 64 + nf * 16 + r15, hi);

        __builtin_amdgcn_s_setprio(1);
        #pragma unroll
        for (int mi = 0; mi < 4; ++mi)
            #pragma unroll
            for (int nf = 0; nf < 4; ++nf)
                acc[mi][nf] = __builtin_amdgcn_mfma_f32_16x16x32_f16(
                    af[mi], bf[nf], acc[mi][nf], 0, 0, 0);
        __builtin_amdgcn_s_setprio(0);

        if (t < nkt - 2) { GATE("3"); } else { GATE("0"); }
        BAR();
    }

    // epilogue: C/D layout col = lane&15, row = (lane>>4)*4 + reg
    #pragma unroll
    for (int nf = 0; nf < 4; ++nf) {
        const size_t col = bn0 + (size_t)(wn * 64 + nf * 16 + r15);
        const float bv = bias[col];
        #pragma unroll
        for (int mi = 0; mi < 4; ++mi) {
            const size_t row0 = bm0 + (size_t)(wm * 64 + mi * 16 + hi * 4);
            #pragma unroll
            for (int r = 0; r < 4; ++r)
                C[(row0 + r) * N + col] = acc[mi][nf][r] + bv;
        }
    }
}

// ---------------------------------------------------------------------------
extern "C" void kernel_launch(void* const* d_in, const int* in_sizes, int n_in,
                              void* d_out, int out_size, void* d_ws, size_t ws_size,
                              hipStream_t stream) {
    const float* x    = (const float*)d_in[0];
    const float* w    = (const float*)d_in[1];
    const float* bias = (const float*)d_in[2];
    const float* aw   = (const float*)d_in[3];
    const float* aA   = (const float*)d_in[4];

    const int    OUT = in_sizes[2];
    const size_t wsz = (size_t)in_sizes[1];
    const int    IN  = (int)(wsz / OUT);
    const int    M   = in_sizes[0] / IN;    // 8192
    const int    N   = OUT;                 // 4096
    const int    K   = IN;                  // 4096

    char* ws = (char*)d_ws;
    _Float16* qx = (_Float16*)ws;                                   // M*K*2
    _Float16* qw = (_Float16*)(ws + (size_t)M * K * 2);             // N*K*2
    float* afeat   = (float*)(ws + (size_t)M * K * 2 + (size_t)N * K * 2);
    float* partial = afeat + K;                                     // 64*K

    const int NCHUNK = 64;
    dim3 g1(K / 1024, NCHUNK);
    colsum_partial4_kernel<<<g1, 256, 0, stream>>>(aA, partial, K, OUT / NCHUNK);
    colsum_final4_kernel<<<K / 1024, 256, 0, stream>>>(partial, afeat, K, NCHUNK,
                                                       1.0f / (float)OUT);

    const size_t nx8 = (size_t)M * K / 8;
    const size_t nw8 = (size_t)N * K / 8;
    quant_xw8_kernel<<<2048, 256, 0, stream>>>(x, afeat, (f16x8*)qx,
                                               w, aw, (f16x8*)qw,
                                               K, nx8, nw8);

    const int nwg = (M / 128) * (N / 256);
    gemm_tlp_kernel<<<nwg, 512, 0, stream>>>(qx, qw, bias, (float*)d_out,
                                             M, N, K);
}

// Round 21
// 368.522 us; speedup vs baseline: 1.1779x; 1.1128x over previous
//
#include <hip/hip_runtime.h>
#include <hip/hip_fp16.h>
#include <cstdint>
#include <cstddef>

typedef _Float16 f16x8 __attribute__((ext_vector_type(8)));
typedef _Float16 f16x4 __attribute__((ext_vector_type(4)));
typedef float    f32x4 __attribute__((ext_vector_type(4)));

// ---------------------------------------------------------------------------
// fake-quant with fractional bit-width interpolation (matches jax reference)
// ---------------------------------------------------------------------------
__device__ __forceinline__ float quant_interp(float v, float alpha) {
    float a    = fmaxf(alpha, 1.0f);
    float blo  = floorf(a);
    float frac = a - blo;
    float slo  = exp2f(blo) - 1.0f;
    float shi  = 2.0f * slo + 1.0f;
    float rslo = __builtin_amdgcn_rcpf(slo);
    float rshi = __builtin_amdgcn_rcpf(shi);
    float c    = fminf(fmaxf(v, -1.0f), 1.0f);
    float qlo  = rintf(c * slo) * rslo;
    float qhi  = rintf(c * shi) * rshi;
    return (1.0f - frac) * qlo + frac * qhi;
}

// ---------------------------------------------------------------------------
// column mean of alpha_a [OUT][IN] -> a_feat [IN] (R18, frozen)
// ---------------------------------------------------------------------------
__global__ void colsum_partial4_kernel(const float* __restrict__ aA,
                                       float* __restrict__ partial,
                                       int IN, int rows_per) {
    int c4 = blockIdx.x * blockDim.x + threadIdx.x;
    size_t r0 = (size_t)blockIdx.y * rows_per;
    f32x4 s = {0.f, 0.f, 0.f, 0.f};
    for (int r = 0; r < rows_per; ++r)
        s += *(const f32x4*)(aA + (r0 + r) * (size_t)IN + (size_t)c4 * 4);
    *(f32x4*)(partial + (size_t)blockIdx.y * IN + (size_t)c4 * 4) = s;
}

__global__ void colsum_final4_kernel(const float* __restrict__ partial,
                                     float* __restrict__ afeat,
                                     int IN, int nchunk, float inv) {
    int c4 = blockIdx.x * blockDim.x + threadIdx.x;
    f32x4 s = {0.f, 0.f, 0.f, 0.f};
    for (int c = 0; c < nchunk; ++c)
        s += *(const f32x4*)(partial + (size_t)c * IN + (size_t)c4 * 4);
    *(f32x4*)(afeat + (size_t)c4 * 4) = s * inv;
}

// ---------------------------------------------------------------------------
// fused quantize (R18, frozen): x hoisted-alpha path + w per-element
// ---------------------------------------------------------------------------
__global__ void quant_xw8_kernel(const float* __restrict__ x,
                                 const float* __restrict__ afeat,
                                 f16x8* __restrict__ qx,
                                 const float* __restrict__ w,
                                 const float* __restrict__ aw,
                                 f16x8* __restrict__ qw,
                                 int IN, size_t nx8, size_t nw8) {
    const size_t t0 = (size_t)blockIdx.x * blockDim.x + threadIdx.x;
    const size_t stride = (size_t)gridDim.x * blockDim.x;

    if (((stride * 8) % (size_t)IN) == 0) {
        const int col = (int)((t0 * 8) % (size_t)IN);
        f32x4 a0 = *(const f32x4*)(afeat + col);
        f32x4 a1 = *(const f32x4*)(afeat + col + 4);
        f32x4 fr0, sl0, rl0, sh0, rh0, fr1, sl1, rl1, sh1, rh1;
        #pragma unroll
        for (int j = 0; j < 4; ++j) {
            float a = fmaxf(a0[j], 1.0f); float b = floorf(a);
            fr0[j] = a - b; sl0[j] = exp2f(b) - 1.0f; sh0[j] = 2.0f * sl0[j] + 1.0f;
            rl0[j] = __builtin_amdgcn_rcpf(sl0[j]);
            rh0[j] = __builtin_amdgcn_rcpf(sh0[j]);
            a = fmaxf(a1[j], 1.0f); b = floorf(a);
            fr1[j] = a - b; sl1[j] = exp2f(b) - 1.0f; sh1[j] = 2.0f * sl1[j] + 1.0f;
            rl1[j] = __builtin_amdgcn_rcpf(sl1[j]);
            rh1[j] = __builtin_amdgcn_rcpf(sh1[j]);
        }
        for (size_t i = t0; i < nx8; i += stride) {
            size_t e = i * 8;
            f32x4 x0 = *(const f32x4*)(x + e);
            f32x4 x1 = *(const f32x4*)(x + e + 4);
            f16x8 o;
            #pragma unroll
            for (int j = 0; j < 4; ++j) {
                float c = fminf(fmaxf(x0[j], -1.0f), 1.0f);
                o[j] = (_Float16)((1.0f - fr0[j]) * (rintf(c * sl0[j]) * rl0[j])
                                  + fr0[j]        * (rintf(c * sh0[j]) * rh0[j]));
            }
            #pragma unroll
            for (int j = 0; j < 4; ++j) {
                float c = fminf(fmaxf(x1[j], -1.0f), 1.0f);
                o[4 + j] = (_Float16)((1.0f - fr1[j]) * (rintf(c * sl1[j]) * rl1[j])
                                      + fr1[j]        * (rintf(c * sh1[j]) * rh1[j]));
            }
            qx[i] = o;
        }
    } else {
        for (size_t i = t0; i < nx8; i += stride) {
            size_t e = i * 8;
            int col = (int)(e % (size_t)IN);
            f32x4 x0 = *(const f32x4*)(x + e);
            f32x4 x1 = *(const f32x4*)(x + e + 4);
            f32x4 a0 = *(const f32x4*)(afeat + col);
            f32x4 a1 = *(const f32x4*)(afeat + col + 4);
            f16x8 o;
            #pragma unroll
            for (int j = 0; j < 4; ++j) o[j]     = (_Float16)quant_interp(x0[j], a0[j]);
            #pragma unroll
            for (int j = 0; j < 4; ++j) o[4 + j] = (_Float16)quant_interp(x1[j], a1[j]);
            qx[i] = o;
        }
    }

    for (size_t i = t0; i < nw8; i += stride) {
        size_t k = i * 8;
        f32x4 w0 = *(const f32x4*)(w + k);
        f32x4 w1 = *(const f32x4*)(w + k + 4);
        f32x4 a0 = *(const f32x4*)(aw + k);
        f32x4 a1 = *(const f32x4*)(aw + k + 4);
        f16x8 o;
        #pragma unroll
        for (int j = 0; j < 4; ++j) o[j]     = (_Float16)quant_interp(w0[j], a0[j]);
        #pragma unroll
        for (int j = 0; j < 4; ++j) o[4 + j] = (_Float16)quant_interp(w1[j], a1[j]);
        qw[i] = o;
    }
}

// ---------------------------------------------------------------------------
// 256x256 NT GEMM, fp16 in / fp32 out — BYTE-EXACT R12/R18 (best measured:
// 250us, MfmaUtil 49.5%, 0 bank conflicts). 2 phases/K-tile, counted vmcnt
// gates (8,6) before each barrier, stages at distance 1/2, XOR slot swizzle
// with inverse on the GLOBAL source (rule #21). NINE schedule/data-path
// variants (lockstep 8/4-phase, barrier-free, A-direct x3, k-slice rotation,
// BK=32 depth-pipeline x2, m201-faithful 4-phase, 2-block/CU TLP) all
// regressed or tied — this point (128x64 wave-tiles, counted gates,
// 1 block/CU) is the measured optimum of the family. FROZEN.
// ---------------------------------------------------------------------------
__device__ __forceinline__ void gload_lds16(const void* g, void* l) {
    __builtin_amdgcn_global_load_lds(
        (const __attribute__((address_space(1))) void*)g,
        (__attribute__((address_space(3))) void*)l, 16, 0, 0);
}

__device__ __forceinline__ f16x8 lds_frag(const _Float16* buf, int row, int ks, int hi) {
    const int sl = (ks * 4 + hi) ^ (row & 7);
    return *(const f16x8*)((const char*)buf + row * 128 + sl * 16);
}

#define GATE(N)  asm volatile("s_waitcnt vmcnt(" N ")" ::: "memory")
#define BAR()    asm volatile("s_barrier" ::: "memory")

#define READ_A(BUF, MH)                                                      \
    _Pragma("unroll")                                                        \
    for (int mi = 0; mi < 4; ++mi) {                                         \
        const int row = (MH) * 128 + wm * 64 + mi * 16 + r15;                \
        af[mi][0] = lds_frag(BUF, row, 0, hi);                               \
        af[mi][1] = lds_frag(BUF, row, 1, hi);                               \
    }

#define READ_BF(BUF)                                                         \
    _Pragma("unroll")                                                        \
    for (int nf = 0; nf < 4; ++nf) {                                         \
        const int row = (nf >> 1) * 128 + wn * 32 + (nf & 1) * 16 + r15;     \
        bf[nf][0] = lds_frag(BUF, row, 0, hi);                               \
        bf[nf][1] = lds_frag(BUF, row, 1, hi);                               \
    }

#define MFMA32(MH)                                                           \
    __builtin_amdgcn_s_setprio(1);                                           \
    _Pragma("unroll")                                                        \
    for (int mi = 0; mi < 4; ++mi)                                           \
        _Pragma("unroll")                                                    \
        for (int nf = 0; nf < 4; ++nf) {                                     \
            f32x4& ac = acc[(MH) * 4 + mi][nf];                              \
            ac = __builtin_amdgcn_mfma_f32_16x16x32_f16(af[mi][0], bf[nf][0], ac, 0, 0, 0); \
            ac = __builtin_amdgcn_mfma_f32_16x16x32_f16(af[mi][1], bf[nf][1], ac, 0, 0, 0); \
        }                                                                    \
    __builtin_amdgcn_s_setprio(0);

// which: 0=A0 1=A1 2=B0 3=B1
#define TILE2(T, G0, G1)                                                     \
  {                                                                          \
    const _Float16* Ab = sA[(T) & 1];                                        \
    const _Float16* Bb = sB[(T) & 1];                                        \
    f16x8 af[4][2];                                                          \
    READ_A(Ab, 0);                                                           \
    READ_BF(Bb);                                                             \
    STAGE((T) + 1, 3); STAGE((T) + 1, 1);                                    \
    MFMA32(0);                                                               \
    GATE(G0); BAR();                                                         \
    READ_A(Ab, 1);                                                           \
    STAGE((T) + 2, 0); STAGE((T) + 2, 2);                                    \
    MFMA32(1);                                                               \
    GATE(G1); BAR();                                                         \
  }

__global__ __launch_bounds__(512, 2) void gemm2pf_kernel(
    const _Float16* __restrict__ A,   // [M][K] qx
    const _Float16* __restrict__ B,   // [N][K] qw
    const float* __restrict__ bias,   // [N]
    float* __restrict__ C,            // [M][N]
    int M, int N, int K)
{
    constexpr int BK = 64;
    __shared__ _Float16 sA[2][256 * BK];   // 64 KiB
    __shared__ _Float16 sB[2][256 * BK];   // 64 KiB

    const int tid  = (int)threadIdx.x;
    const int lane = tid & 63;
    const int wave = tid >> 6;
    const int wm   = wave >> 2;    // 0..1
    const int wn   = wave & 3;     // 0..3
    const int r15  = lane & 15;
    const int hi   = lane >> 4;

    const int nbx = N >> 8;
    const int nwg = (M >> 8) * nbx;
    const int bid = (int)blockIdx.x;
    const int swz = (nwg & 7) ? bid : ((bid & 7) * (nwg >> 3) + (bid >> 3));
    const size_t bm0 = (size_t)(swz / nbx) << 8;
    const size_t bn0 = (size_t)(swz % nbx) << 8;

    const int nkt = K / BK;
    const _Float16* Agb = A + bm0 * K;
    const _Float16* Bgb = B + bn0 * K;

    auto STAGE = [&](int tile, int which) {
        if (tile >= nkt) return;
        const _Float16* g = (which < 2 ? Agb : Bgb) + (size_t)tile * BK;
        _Float16* lb = (which < 2 ? sA[tile & 1] : sB[tile & 1]);
        const int rb = (which & 1) << 7;
        #pragma unroll
        for (int rr = 0; rr < 2; ++rr) {
            const int row = rb + rr * 64 + (tid >> 3);
            const int sg  = (tid & 7) ^ (row & 7);
            gload_lds16(g + (size_t)row * K + sg * 8,
                        (char*)lb + ((rb + rr * 64) << 7) + (wave << 10));
        }
    };

    f32x4 acc[8][4] = {};
    f16x8 bf[4][2];

    // prologue: A0(0),B0(0),B1(0),A1(0),A0(1),B0(1) = 12 loads;
    // vmcnt(6) drains tile0's A0,B0,B1; leaves [A1(0),A0(1),B0(1)] in flight
    STAGE(0, 0); STAGE(0, 2); STAGE(0, 3); STAGE(0, 1);
    STAGE(1, 0); STAGE(1, 2);
    GATE("6"); BAR();

    int t = 0;
    for (; t < nkt - 3; ++t)
        TILE2(t, "8", "6");
    for (; t < nkt; ++t)           // tail: stages skip -> full drain is safe
        TILE2(t, "0", "0");

    // epilogue: C/D layout col = lane&15, row = (lane>>4)*4 + reg
    #pragma unroll
    for (int nf = 0; nf < 4; ++nf) {
        const size_t col = bn0 + (size_t)((nf >> 1) * 128 + wn * 32 + (nf & 1) * 16 + r15);
        const float bv = bias[col];
        #pragma unroll
        for (int mf = 0; mf < 8; ++mf) {
            const size_t row0 = bm0 + (size_t)((mf >> 2) * 128 + wm * 64 + (mf & 3) * 16 + hi * 4);
            #pragma unroll
            for (int r = 0; r < 4; ++r)
                C[(row0 + r) * N + col] = acc[mf][nf][r] + bv;
        }
    }
}

// ---------------------------------------------------------------------------
extern "C" void kernel_launch(void* const* d_in, const int* in_sizes, int n_in,
                              void* d_out, int out_size, void* d_ws, size_t ws_size,
                              hipStream_t stream) {
    const float* x    = (const float*)d_in[0];
    const float* w    = (const float*)d_in[1];
    const float* bias = (const float*)d_in[2];
    const float* aw   = (const float*)d_in[3];
    const float* aA   = (const float*)d_in[4];

    const int    OUT = in_sizes[2];
    const size_t wsz = (size_t)in_sizes[1];
    const int    IN  = (int)(wsz / OUT);
    const int    M   = in_sizes[0] / IN;    // 8192
    const int    N   = OUT;                 // 4096
    const int    K   = IN;                  // 4096

    char* ws = (char*)d_ws;
    _Float16* qx = (_Float16*)ws;                                   // M*K*2
    _Float16* qw = (_Float16*)(ws + (size_t)M * K * 2);             // N*K*2
    float* afeat   = (float*)(ws + (size_t)M * K * 2 + (size_t)N * K * 2);
    float* partial = afeat + K;                                     // 64*K

    const int NCHUNK = 64;
    dim3 g1(K / 1024, NCHUNK);
    colsum_partial4_kernel<<<g1, 256, 0, stream>>>(aA, partial, K, OUT / NCHUNK);
    colsum_final4_kernel<<<K / 1024, 256, 0, stream>>>(partial, afeat, K, NCHUNK,
                                                       1.0f / (float)OUT);

    const size_t nx8 = (size_t)M * K / 8;
    const size_t nw8 = (size_t)N * K / 8;
    quant_xw8_kernel<<<2048, 256, 0, stream>>>(x, afeat, (f16x8*)qx,
                                               w, aw, (f16x8*)qw,
                                               K, nx8, nw8);

    const int nwg = (M / 256) * (N / 256);
    gemm2pf_kernel<<<nwg, 512, 0, stream>>>(qx, qw, bias, (float*)d_out,
                                            M, N, K);
}